// Round 16
// baseline (68.981 us; speedup 1.0000x reference)
//
#include <hip/hip_runtime.h>

// MatrixMLP round 16: r15 (slim, transposed-MFMA, packed writes) with the
// block barriers replaced by per-wave lgkmcnt fences (r6 wave-autonomy).
//  - r12/r13 falsified "asm memory-clobber causes spills": the trigger was
//    non-SROA'd local arrays, all eliminated since r13.  With nothing left
//    to demote, the asm fence is safe, and removing 14 block-wide barriers
//    un-lockstepps the 4 waves (r15: 35% VALUBusy, 17% occupancy,
//    barrier-bound).
//  - Waves only touch their own LDS chunk; intra-wave DS is FIFO, so the
//    fence is purely a compiler reordering barrier (r6/r7 passed with it).
//  - Kill-switch: if hot WRITE_SIZE balloons again, revert to r14.

typedef __attribute__((ext_vector_type(8))) short short8;
typedef __attribute__((ext_vector_type(4))) short short4v;   // 8 B
typedef __attribute__((ext_vector_type(4))) float f32x4;

#define WAVE_FENCE() asm volatile("s_waitcnt lgkmcnt(0)" ::: "memory")

__device__ __forceinline__ short f2bf(float f) {
  unsigned int u = __float_as_uint(f);
  u += 0x7fffu + ((u >> 16) & 1u);
  return (short)(u >> 16);
}
__device__ __forceinline__ float cl01(float v) {
  if (v != v) v = 0.0f;
  return fminf(fmaxf(v, 0.0f), 1.0f);
}

#define GUARD_THETA 1.0e-4f
#define WFRAG_BYTES 26624        // 26 frags * 64 lanes * 16 B
#define WL_CNT_OFF  26624        // 32 counters, stride 32 ints (128 B)
#define WL_LIST_OFF 30720
#define NBUCK 32
#define RBLK 256

// ---- per-wave LDS chunk (bytes) ----
#define W_A    0        // 64 rows * 80 B
#define W_H1   5120     // 16 rows * 272 B
#define W_H2   9472     // 16 rows * 144 B
#define W_D    11776    // 64 rows * 20 B
#define W_SZ   13056
#define SMEM_SZ (4 * W_SZ)   // 52224 B -> 3 blocks/CU

// ---------------- weight fragment pre-pack (+ counter reset) ----------------
__global__ void pack_w(const float* __restrict__ W1, const float* __restrict__ W2,
                       const float* __restrict__ W3, short* __restrict__ ws,
                       int* __restrict__ wl_cnt)
{
  if (wl_cnt && blockIdx.x == 0 && threadIdx.x < NBUCK)
    wl_cnt[threadIdx.x * 32] = 0;
  int t = blockIdx.x * 256 + threadIdx.x;
  if (t >= 26 * 64) return;
  int fid = t >> 6, lane = t & 63, l15 = lane & 15, lg = lane >> 4;
  short8 v;
  if (fid < 8) {
    int col = fid * 16 + l15;
    #pragma unroll
    for (int j = 0; j < 8; ++j) {
      int k = lg * 8 + j;
      v[j] = (k < 24) ? f2bf(W1[k * 128 + col]) : (short)0;
    }
  } else if (fid < 24) {
    int q = fid - 8, kt = q >> 2, nt = q & 3, col = nt * 16 + l15;
    #pragma unroll
    for (int j = 0; j < 8; ++j)
      v[j] = f2bf(W2[(kt * 32 + lg * 8 + j) * 64 + col]);
  } else {
    int kt = fid - 24;
    #pragma unroll
    for (int j = 0; j < 8; ++j)
      v[j] = (l15 < 4) ? f2bf(W3[(kt * 32 + lg * 8 + j) * 4 + l15]) : (short)0;
  }
  ((short8*)ws)[t] = v;
}

// ---------------- shared MFMA MLP body (wave-autonomous, transposed) --------
// D = mfma(Wfrag, Datafrag) = H^T.  C/D layout (m89): c=l15 -> row m of H,
// r=4*lg+reg -> col n.  Lane (l15,lg) holds H[m=t*16+l15][nt*16+4lg .. +3].
template <bool WF>
__device__ __forceinline__ void mlp_wave(
    unsigned char* wsm, int lane, int l15, int lg,
    const short8* __restrict__ wv4,
    const float* __restrict__ W1, const float* __restrict__ W2,
    const float* __restrict__ W3,
    const float* __restrict__ b1, const float* __restrict__ b2,
    const float* __restrict__ b3)
{
  const f32x4 fzero = {0.0f, 0.0f, 0.0f, 0.0f};

  short8 bf1[8];
  if constexpr (WF) {
    #pragma unroll
    for (int nt = 0; nt < 8; ++nt) bf1[nt] = wv4[nt * 64 + lane];
  } else {
    #pragma unroll
    for (int nt = 0; nt < 8; ++nt) {
      int col = nt * 16 + l15;
      #pragma unroll
      for (int j = 0; j < 8; ++j) {
        int k = lg * 8 + j;
        bf1[nt][j] = (k < 24) ? f2bf(W1[k * 128 + col]) : (short)0;
      }
    }
  }
  const f32x4 b3v = *(const f32x4*)b3;   // used by lg==0 lanes

  WAVE_FENCE();   // A-rows of this wave visible (intra-wave DS is FIFO)

  for (int t = 0; t < 4; ++t) {
    // ---- layer 1: H1^T tiles = mfma(W1frag, Afrag) + b1, ReLU ----
    {
      short8 a = *(const short8*)(wsm + W_A + (t * 16 + l15) * 80 + lg * 16);
      f32x4 acc[8];
      #pragma unroll
      for (int nt = 0; nt < 8; ++nt)
        acc[nt] = __builtin_amdgcn_mfma_f32_16x16x32_bf16(bf1[nt], a, fzero, 0, 0, 0);
      #pragma unroll
      for (int nt = 0; nt < 8; ++nt) {
        const f32x4 bv = *(const f32x4*)(b1 + nt * 16 + lg * 4);
        short4v pk;
        #pragma unroll
        for (int j = 0; j < 4; ++j) {
          float h = acc[nt][j] + bv[j];
          h = h > 0.0f ? h : 0.0f;
          pk[j] = f2bf(h);
        }
        *(short4v*)(wsm + W_H1 + l15 * 272 + (nt * 16 + lg * 4) * 2) = pk;
      }
    }
    WAVE_FENCE();

    // ---- layer 2: H2^T tiles = mfma(W2frag, H1frag) + b2, ReLU ----
    {
      f32x4 acc2[4] = {fzero, fzero, fzero, fzero};
      #pragma unroll
      for (int kt = 0; kt < 4; ++kt) {
        short8 a2 = *(const short8*)(wsm + W_H1 + l15 * 272 + kt * 64 + lg * 16);
        #pragma unroll
        for (int nt = 0; nt < 4; ++nt) {
          short8 bw;
          if constexpr (WF) {
            bw = wv4[(8 + kt * 4 + nt) * 64 + lane];
          } else {
            int col = nt * 16 + l15;
            #pragma unroll
            for (int j = 0; j < 8; ++j)
              bw[j] = f2bf(W2[(kt * 32 + lg * 8 + j) * 64 + col]);
          }
          acc2[nt] = __builtin_amdgcn_mfma_f32_16x16x32_bf16(bw, a2, acc2[nt], 0, 0, 0);
        }
      }
      #pragma unroll
      for (int nt = 0; nt < 4; ++nt) {
        const f32x4 bv = *(const f32x4*)(b2 + nt * 16 + lg * 4);
        short4v pk;
        #pragma unroll
        for (int j = 0; j < 4; ++j) {
          float h = acc2[nt][j] + bv[j];
          h = h > 0.0f ? h : 0.0f;
          pk[j] = f2bf(h);
        }
        *(short4v*)(wsm + W_H2 + l15 * 144 + (nt * 16 + lg * 4) * 2) = pk;
      }
    }
    WAVE_FENCE();

    // ---- layer 3: delta^T = mfma(W3frag, H2frag) + b3 ----
    {
      f32x4 acc3 = fzero;
      #pragma unroll
      for (int kt = 0; kt < 2; ++kt) {
        short8 a3 = *(const short8*)(wsm + W_H2 + l15 * 144 + kt * 64 + lg * 16);
        short8 bw;
        if constexpr (WF) {
          bw = wv4[(24 + kt) * 64 + lane];
        } else {
          #pragma unroll
          for (int j = 0; j < 8; ++j)
            bw[j] = (l15 < 4) ? f2bf(W3[(kt * 32 + lg * 8 + j) * 4 + l15]) : (short)0;
        }
        acc3 = __builtin_amdgcn_mfma_f32_16x16x32_bf16(bw, a3, acc3, 0, 0, 0);
      }
      if (lg == 0) {
        float* dr = (float*)(wsm + W_D + (t * 16 + l15) * 20);
        #pragma unroll
        for (int j = 0; j < 4; ++j) dr[j] = acc3[j] + b3v[j];
      }
    }
    WAVE_FENCE();   // orders next t's H1 writes behind this t's H2/delta
  }
}

// ---------------- hot kernel (slim + in-kernel worklist append) -------------
__global__ __launch_bounds__(256, 2) void MatrixMLP_54047868453544_kernel(
    const float* __restrict__ x,
    const float* __restrict__ b1, const float* __restrict__ b2,
    const float* __restrict__ b3,
    const short* __restrict__ wfrag,
    int* __restrict__ wl_cnt, int* __restrict__ wl_list,
    int nbuck, int cap,
    float* __restrict__ out, int Bn)
{
  __shared__ __align__(16) unsigned char smem[SMEM_SZ];
  const int tid  = threadIdx.x;
  const int lane = tid & 63;
  const int wv   = tid >> 6;
  const int l15  = lane & 15;
  const int lg   = lane >> 4;
  unsigned char* wsm = smem + wv * W_SZ;
  const long long g = (long long)blockIdx.x * 256 + wv * 64 + lane;
  const f32x4 fzero = {0.0f, 0.0f, 0.0f, 0.0f};

  // ---- load row as named vectors ----
  f32x4 v0 = fzero, v1 = fzero, v2 = fzero, v3 = fzero, v4 = fzero;
  if (g < Bn) {
    const f32x4* xr = (const f32x4*)(x + g * 20);
    v0 = xr[0]; v1 = xr[1]; v2 = xr[2]; v3 = xr[3]; v4 = xr[4];
  }

  // ---- f32 Cramer solve with safety guard; all named scalars ----
  float a00 = v0[0], a10 = v0[1], a20 = v0[2], a30 = v0[3];
  float a01 = v1[0], a11 = v1[1], a21 = v1[2], a31 = v1[3];
  float a02 = v2[0], a12 = v2[1], a22 = v2[2], a32 = v2[3];
  float a03 = v3[0], a13 = v3[1], a23 = v3[2], a33 = v3[3];
  float y0 = v4[0], y1 = v4[1], y2 = v4[2], y3 = v4[3];

  float s0 = a00*a11 - a10*a01, s1 = a00*a12 - a10*a02, s2 = a00*a13 - a10*a03;
  float s3 = a01*a12 - a11*a02, s4 = a01*a13 - a11*a03, s5 = a02*a13 - a12*a03;
  float c0 = a20*a31 - a30*a21, c1 = a20*a32 - a30*a22, c2 = a20*a33 - a30*a23;
  float c3 = a21*a32 - a31*a22, c4 = a21*a33 - a31*a23, c5 = a22*a33 - a32*a23;
  float det = s0*c5 - s1*c4 + s2*c3 + s3*c2 - s4*c1 + s5*c0;
  float T = a00*a00 + a01*a01 + a02*a02 + a03*a03
          + a10*a10 + a11*a11 + a12*a12 + a13*a13
          + a20*a20 + a21*a21 + a22*a22 + a23*a23
          + a30*a30 + a31*a31 + a32*a32 + a33*a33;

  const bool safe = __builtin_fabsf(det) > GUARD_THETA * T * T;
  float xd0 = 0.0f, xd1 = 0.0f, xd2 = 0.0f, xd3 = 0.0f;
  if (safe) {
    float rdet = 1.0f / det;
    xd0 = rdet * ((  a11*c5 - a12*c4 + a13*c3) * y0 +
                  (-(a01*c5 - a02*c4 + a03*c3)) * y1 +
                  (  a31*s5 - a32*s4 + a33*s3) * y2 +
                  (-(a21*s5 - a22*s4 + a23*s3)) * y3);
    xd1 = rdet * ((-(a10*c5 - a12*c2 + a13*c1)) * y0 +
                  (  a00*c5 - a02*c2 + a03*c1) * y1 +
                  (-(a30*s5 - a32*s2 + a33*s1)) * y2 +
                  (  a20*s5 - a22*s2 + a23*s1) * y3);
    xd2 = rdet * ((  a10*c4 - a11*c2 + a13*c0) * y0 +
                  (-(a00*c4 - a01*c2 + a03*c0)) * y1 +
                  (  a30*s4 - a31*s2 + a33*s0) * y2 +
                  (-(a20*s4 - a21*s2 + a23*s0)) * y3);
    xd3 = rdet * ((-(a10*c3 - a11*c1 + a12*c0)) * y0 +
                  (  a00*c3 - a01*c1 + a02*c0) * y1 +
                  (-(a30*s3 - a31*s1 + a32*s0)) * y2 +
                  (  a20*s3 - a21*s1 + a22*s0) * y3);
  }
  // unsafe lanes keep xd=0: placeholder, overwritten by repair kernel

  // ---- worklist append: EXACT predicate, 1 bucketed atomic per wave ----
  if (wl_list) {
    const bool unsafe_row = (!safe) && (g < Bn);
    unsigned long long m = __ballot(unsafe_row);
    if (m) {
      const int bucket = (int)blockIdx.x % nbuck;
      int leader = (int)__builtin_ctzll(m);
      int base = 0;
      if (lane == leader)
        base = atomicAdd(&wl_cnt[bucket * 32], (int)__builtin_popcountll(m));
      base = __shfl(base, leader, 64);
      if (unsafe_row) {
        int lt = (int)__builtin_popcountll(m & ((1ull << lane) - 1ull));
        wl_list[(size_t)bucket * cap + base + lt] = (int)g;
      }
    }
  }

  const float xls0 = cl01(xd0), xls1 = cl01(xd1);
  const float xls2 = cl01(xd2), xls3 = cl01(xd3);

  // ---- A-row as named short8 vectors ----
  short8 r0 = { f2bf(v0[0]), f2bf(v0[1]), f2bf(v0[2]), f2bf(v0[3]),
                f2bf(v1[0]), f2bf(v1[1]), f2bf(v1[2]), f2bf(v1[3]) };
  short8 r1 = { f2bf(v2[0]), f2bf(v2[1]), f2bf(v2[2]), f2bf(v2[3]),
                f2bf(v3[0]), f2bf(v3[1]), f2bf(v3[2]), f2bf(v3[3]) };
  short8 r2 = { f2bf(v4[0]), f2bf(v4[1]), f2bf(v4[2]), f2bf(v4[3]),
                f2bf(xls0),  f2bf(xls1),  f2bf(xls2),  f2bf(xls3) };
  short8 r3 = { 0, 0, 0, 0, 0, 0, 0, 0 };
  {
    short8* dst = (short8*)(wsm + W_A + lane * 80);
    dst[0] = r0; dst[1] = r1; dst[2] = r2; dst[3] = r3;
  }

  // ---- MFMA MLP (wave-autonomous, transposed, packed epilogues) ----
  mlp_wave<true>(wsm, lane, l15, lg, (const short8*)wfrag,
                 nullptr, nullptr, nullptr, b1, b2, b3);

  // ---- epilogue ----
  if (g < Bn) {
    const float* dl = (const float*)(wsm + W_D + lane * 20);
    f32x4 o = { fminf(fmaxf(xls0 + dl[0], 0.0f), 1.0f),
                fminf(fmaxf(xls1 + dl[1], 0.0f), 1.0f),
                fminf(fmaxf(xls2 + dl[2], 0.0f), 1.0f),
                fminf(fmaxf(xls3 + dl[3], 0.0f), 1.0f) };
    *(f32x4*)(out + g * 4) = o;
  }
}

// ---------------- repair kernel (parallel buckets / full-scan fallback) -----
__global__ __launch_bounds__(256) void repair_rows(
    const float* __restrict__ x,
    const float* __restrict__ W1, const float* __restrict__ b1,
    const float* __restrict__ W2, const float* __restrict__ b2,
    const float* __restrict__ W3, const float* __restrict__ b3,
    const short* __restrict__ wfrag,
    float* __restrict__ out, int Bn,
    const int* __restrict__ wl_cnt, const int* __restrict__ wl_list,
    int use_wl, int nbuck, int cap, int write_all)
{
  __shared__ __align__(16) unsigned char smem[SMEM_SZ];
  const int tid  = threadIdx.x;
  const int lane = tid & 63;
  const int wv   = tid >> 6;
  const int l15  = lane & 15;
  const int lg   = lane >> 4;
  unsigned char* wsm = smem + wv * W_SZ;

  const int bucket = use_wl ? ((int)blockIdx.x % nbuck) : 0;
  const int sub    = use_wl ? ((int)blockIdx.x / nbuck) : (int)blockIdx.x;
  const int nsub   = use_wl ? ((int)gridDim.x / nbuck)  : (int)gridDim.x;
  const int cnt = use_wl ? wl_cnt[bucket * 32] : Bn;
  const int* lst = wl_list + (size_t)bucket * cap;

  for (long long blk0 = (long long)sub * 256; blk0 < cnt;
       blk0 += (long long)nsub * 256) {
    const long long idx = blk0 + tid;
    int g = -1;
    if (idx < cnt) g = use_wl ? lst[idx] : (int)idx;

    float xf[20];
    if (g >= 0) {
      const float* xr = x + (long long)g * 20;
      #pragma unroll
      for (int i = 0; i < 5; ++i) {
        f32x4 v = *(const f32x4*)(xr + i * 4);
        xf[i*4+0] = v[0]; xf[i*4+1] = v[1]; xf[i*4+2] = v[2]; xf[i*4+3] = v[3];
      }
    } else {
      #pragma unroll
      for (int i = 0; i < 20; ++i) xf[i] = 0.0f;
    }

    if (!use_wl && !write_all && g >= 0) {
      // scan fallback with hot kernel present: keep only guard-failing rows
      float a00 = xf[0], a01 = xf[4], a02 = xf[8],  a03 = xf[12];
      float a10 = xf[1], a11 = xf[5], a12 = xf[9],  a13 = xf[13];
      float a20 = xf[2], a21 = xf[6], a22 = xf[10], a23 = xf[14];
      float a30 = xf[3], a31 = xf[7], a32 = xf[11], a33 = xf[15];
      float s0 = a00*a11 - a10*a01, s1 = a00*a12 - a10*a02, s2 = a00*a13 - a10*a03;
      float s3 = a01*a12 - a11*a02, s4 = a01*a13 - a11*a03, s5 = a02*a13 - a12*a03;
      float c0 = a20*a31 - a30*a21, c1 = a20*a32 - a30*a22, c2 = a20*a33 - a30*a23;
      float c3 = a21*a32 - a31*a22, c4 = a21*a33 - a31*a23, c5 = a22*a33 - a32*a23;
      float det = s0*c5 - s1*c4 + s2*c3 + s3*c2 - s4*c1 + s5*c0;
      float T = a00*a00 + a01*a01 + a02*a02 + a03*a03
              + a10*a10 + a11*a11 + a12*a12 + a13*a13
              + a20*a20 + a21*a21 + a22*a22 + a23*a23
              + a30*a30 + a31*a31 + a32*a32 + a33*a33;
      if (__builtin_fabsf(det) > GUARD_THETA * 1.004f * T * T) g = -1;
    }

    // ---- f64 Jacobi eigensolve of G = H^T H + jax rcond truncation ----
    double G[4][4], V[4][4], rhs[4];
    #pragma unroll
    for (int p = 0; p < 4; ++p) {
      #pragma unroll
      for (int q = 0; q < 4; ++q) {
        double s = 0.0;
        #pragma unroll
        for (int k = 0; k < 4; ++k)
          s += (double)xf[p * 4 + k] * (double)xf[q * 4 + k];
        G[p][q] = s;
        V[p][q] = (p == q) ? 1.0 : 0.0;
      }
      double s = 0.0;
      #pragma unroll
      for (int k = 0; k < 4; ++k) s += (double)xf[p * 4 + k] * (double)xf[16 + k];
      rhs[p] = s;
    }
    #pragma unroll 1
    for (int sweep = 0; sweep < 6; ++sweep) {
      #pragma unroll
      for (int pq = 0; pq < 6; ++pq) {
        constexpr int PP[6] = {0, 0, 0, 1, 1, 2};
        constexpr int QQ[6] = {1, 2, 3, 2, 3, 3};
        const int p = PP[pq], q = QQ[pq];
        double apq = G[p][q];
        double c, s;
        if (apq != 0.0) {
          double tau = (G[q][q] - G[p][p]) / (2.0 * apq);
          double t = (tau >= 0.0 ? 1.0 : -1.0) / (fabs(tau) + sqrt(1.0 + tau * tau));
          c = 1.0 / sqrt(1.0 + t * t);
          s = t * c;
        } else { c = 1.0; s = 0.0; }
        #pragma unroll
        for (int k = 0; k < 4; ++k) {
          double gpk = G[p][k], gqk = G[q][k];
          G[p][k] = c * gpk - s * gqk;
          G[q][k] = s * gpk + c * gqk;
        }
        #pragma unroll
        for (int k = 0; k < 4; ++k) {
          double gkp = G[k][p], gkq = G[k][q];
          G[k][p] = c * gkp - s * gkq;
          G[k][q] = s * gkp + c * gkq;
        }
        #pragma unroll
        for (int k = 0; k < 4; ++k) {
          double vkp = V[k][p], vkq = V[k][q];
          V[k][p] = c * vkp - s * vkq;
          V[k][q] = s * vkp + c * vkq;
        }
      }
    }
    double lam[4] = {G[0][0], G[1][1], G[2][2], G[3][3]};
    double lmax = fmax(fmax(lam[0], lam[1]), fmax(lam[2], lam[3]));
    lmax = fmax(lmax, 0.0);
    const double cut = 2.27373675443232e-11 * lmax;  // (4.7683716e-6)^2
    double xd0 = 0.0, xd1 = 0.0, xd2 = 0.0, xd3 = 0.0;
    #pragma unroll
    for (int k = 0; k < 4; ++k) {
      if (lam[k] > cut && lam[k] > 0.0) {
        double coef = (V[0][k] * rhs[0] + V[1][k] * rhs[1] +
                       V[2][k] * rhs[2] + V[3][k] * rhs[3]) / lam[k];
        xd0 += V[0][k] * coef;
        xd1 += V[1][k] * coef;
        xd2 += V[2][k] * coef;
        xd3 += V[3][k] * coef;
      }
    }

    float xls[4];
    {
      double xd[4] = {xd0, xd1, xd2, xd3};
      short rowbuf[32];
      #pragma unroll
      for (int i = 0; i < 20; ++i) rowbuf[i] = f2bf(xf[i]);
      #pragma unroll
      for (int i = 0; i < 4; ++i) {
        float v = (float)xd[i];
        if (v != v) v = 0.0f;
        v = fminf(fmaxf(v, 0.0f), 1.0f);
        xls[i] = v;
        rowbuf[20 + i] = f2bf(v);
      }
      #pragma unroll
      for (int i = 24; i < 32; ++i) rowbuf[i] = 0;
      short8* dst = (short8*)(wsm + W_A + lane * 80);
      #pragma unroll
      for (int i = 0; i < 4; ++i) dst[i] = *(short8*)(rowbuf + i * 8);
    }

    if (wfrag)
      mlp_wave<true>(wsm, lane, l15, lg, (const short8*)wfrag,
                     W1, W2, W3, b1, b2, b3);
    else
      mlp_wave<false>(wsm, lane, l15, lg, nullptr,
                      W1, W2, W3, b1, b2, b3);

    if (g >= 0) {
      const float* dl = (const float*)(wsm + W_D + lane * 20);
      f32x4 o = { fminf(fmaxf(xls[0] + dl[0], 0.0f), 1.0f),
                  fminf(fmaxf(xls[1] + dl[1], 0.0f), 1.0f),
                  fminf(fmaxf(xls[2] + dl[2], 0.0f), 1.0f),
                  fminf(fmaxf(xls[3] + dl[3], 0.0f), 1.0f) };
      *(f32x4*)(out + (long long)g * 4) = o;
    }
  }
}

extern "C" void kernel_launch(void* const* d_in, const int* in_sizes, int n_in,
                              void* d_out, int out_size, void* d_ws, size_t ws_size,
                              hipStream_t stream) {
  (void)n_in;
  const float* x  = (const float*)d_in[0];
  const float* W1 = (const float*)d_in[1];
  const float* b1 = (const float*)d_in[2];
  const float* W2 = (const float*)d_in[3];
  const float* b2 = (const float*)d_in[4];
  const float* W3 = (const float*)d_in[5];
  const float* b3 = (const float*)d_in[6];
  float* out = (float*)d_out;
  const int Bn = in_sizes[0] / 20;
  const int nblk = (Bn + 255) / 256;

  short* wfrag = nullptr;
  int* wl_cnt = nullptr;
  int* wl_list = nullptr;
  int use_wl = 0, nbuck = 1, cap = 0;
  if (ws_size >= (size_t)WFRAG_BYTES) wfrag = (short*)d_ws;
  {
    int cap32 = 256 * ((nblk + NBUCK - 1) / NBUCK);
    int cap1  = 256 * nblk;
    if (ws_size >= (size_t)WL_LIST_OFF + 4ull * NBUCK * (size_t)cap32) {
      nbuck = NBUCK; cap = cap32; use_wl = 1;
    } else if (ws_size >= (size_t)WL_LIST_OFF + 4ull * (size_t)cap1) {
      nbuck = 1; cap = cap1; use_wl = 1;
    }
    if (use_wl) {
      wl_cnt  = (int*)((char*)d_ws + WL_CNT_OFF);
      wl_list = (int*)((char*)d_ws + WL_LIST_OFF);
    }
  }

  (void)hipGetLastError();

  if (wfrag) {
    pack_w<<<7, 256, 0, stream>>>(W1, W2, W3, wfrag, wl_cnt);
    MatrixMLP_54047868453544_kernel<<<nblk, 256, 0, stream>>>(
        x, b1, b2, b3, wfrag,
        use_wl ? wl_cnt : nullptr, use_wl ? wl_list : nullptr,
        nbuck, cap, out, Bn);
    const int rblk = use_wl ? (nbuck * (RBLK / NBUCK)) : RBLK;
    repair_rows<<<rblk, 256, 0, stream>>>(x, W1, b1, W2, b2, W3, b3, wfrag,
                                          out, Bn, wl_cnt, wl_list,
                                          use_wl, nbuck, cap, /*write_all=*/0);
  } else {
    // ws too small for weight fragments (never observed): full Jacobi+MFMA
    // pass over ALL rows -- slow but correct.
    repair_rows<<<RBLK, 256, 0, stream>>>(x, W1, b1, W2, b2, W3, b3, nullptr,
                                          out, Bn, nullptr, nullptr,
                                          /*use_wl=*/0, 1, 0, /*write_all=*/1);
  }

  hipError_t e = hipGetLastError();
  if (e != hipSuccess) {
    int byte = 0x40 + ((int)e & 63);
    hipMemsetAsync(d_out, byte, (size_t)out_size * sizeof(float), stream);
  }
}

// Round 17
// 64.722 us; speedup vs baseline: 1.0658x; 1.0658x over previous
//
#include <hip/hip_runtime.h>

// MatrixMLP round 17: r16 + PRELOADED bias registers.
//  - r15/r16 regression diagnosed: bias loads moved into the epilogue loops
//    (48 in-loop f32x4 global loads/thread on the dependent chain; VGPR=80
//    proves un-hoisted).  r14 preloaded biases and its hot kernel was <40us.
//  - Fix: bias1v[8]/bias2v[4]/b3v preloaded as named f32x4 registers before
//    the t-loop.  Transposed MFMA + packed b64 writes + wave fences kept.

typedef __attribute__((ext_vector_type(8))) short short8;
typedef __attribute__((ext_vector_type(4))) short short4v;   // 8 B
typedef __attribute__((ext_vector_type(4))) float f32x4;

#define WAVE_FENCE() asm volatile("s_waitcnt lgkmcnt(0)" ::: "memory")

__device__ __forceinline__ short f2bf(float f) {
  unsigned int u = __float_as_uint(f);
  u += 0x7fffu + ((u >> 16) & 1u);
  return (short)(u >> 16);
}
__device__ __forceinline__ float cl01(float v) {
  if (v != v) v = 0.0f;
  return fminf(fmaxf(v, 0.0f), 1.0f);
}

#define GUARD_THETA 1.0e-4f
#define WFRAG_BYTES 26624        // 26 frags * 64 lanes * 16 B
#define WL_CNT_OFF  26624        // 32 counters, stride 32 ints (128 B)
#define WL_LIST_OFF 30720
#define NBUCK 32
#define RBLK 256

// ---- per-wave LDS chunk (bytes) ----
#define W_A    0        // 64 rows * 80 B
#define W_H1   5120     // 16 rows * 272 B
#define W_H2   9472     // 16 rows * 144 B
#define W_D    11776    // 64 rows * 20 B
#define W_SZ   13056
#define SMEM_SZ (4 * W_SZ)   // 52224 B -> 3 blocks/CU

// ---------------- weight fragment pre-pack (+ counter reset) ----------------
__global__ void pack_w(const float* __restrict__ W1, const float* __restrict__ W2,
                       const float* __restrict__ W3, short* __restrict__ ws,
                       int* __restrict__ wl_cnt)
{
  if (wl_cnt && blockIdx.x == 0 && threadIdx.x < NBUCK)
    wl_cnt[threadIdx.x * 32] = 0;
  int t = blockIdx.x * 256 + threadIdx.x;
  if (t >= 26 * 64) return;
  int fid = t >> 6, lane = t & 63, l15 = lane & 15, lg = lane >> 4;
  short8 v;
  if (fid < 8) {
    int col = fid * 16 + l15;
    #pragma unroll
    for (int j = 0; j < 8; ++j) {
      int k = lg * 8 + j;
      v[j] = (k < 24) ? f2bf(W1[k * 128 + col]) : (short)0;
    }
  } else if (fid < 24) {
    int q = fid - 8, kt = q >> 2, nt = q & 3, col = nt * 16 + l15;
    #pragma unroll
    for (int j = 0; j < 8; ++j)
      v[j] = f2bf(W2[(kt * 32 + lg * 8 + j) * 64 + col]);
  } else {
    int kt = fid - 24;
    #pragma unroll
    for (int j = 0; j < 8; ++j)
      v[j] = (l15 < 4) ? f2bf(W3[(kt * 32 + lg * 8 + j) * 4 + l15]) : (short)0;
  }
  ((short8*)ws)[t] = v;
}

// ---------------- shared MFMA MLP body (wave-autonomous, transposed) --------
// D = mfma(Wfrag, Datafrag) = H^T.  C/D layout (m89): c=l15 -> row m of H,
// r=4*lg+reg -> col n.  Lane (l15,lg) holds H[m=t*16+l15][nt*16+4lg .. +3].
template <bool WF>
__device__ __forceinline__ void mlp_wave(
    unsigned char* wsm, int lane, int l15, int lg,
    const short8* __restrict__ wv4,
    const float* __restrict__ W1, const float* __restrict__ W2,
    const float* __restrict__ W3,
    const float* __restrict__ b1, const float* __restrict__ b2,
    const float* __restrict__ b3)
{
  const f32x4 fzero = {0.0f, 0.0f, 0.0f, 0.0f};

  short8 bf1[8];
  if constexpr (WF) {
    #pragma unroll
    for (int nt = 0; nt < 8; ++nt) bf1[nt] = wv4[nt * 64 + lane];
  } else {
    #pragma unroll
    for (int nt = 0; nt < 8; ++nt) {
      int col = nt * 16 + l15;
      #pragma unroll
      for (int j = 0; j < 8; ++j) {
        int k = lg * 8 + j;
        bf1[nt][j] = (k < 24) ? f2bf(W1[k * 128 + col]) : (short)0;
      }
    }
  }
  // ---- PRELOADED biases (statically indexed -> registers, hoisted off the
  //      epilogue dependent chains; this was the r15/r16 regression) ----
  f32x4 bias1v[8];
  #pragma unroll
  for (int nt = 0; nt < 8; ++nt) bias1v[nt] = *(const f32x4*)(b1 + nt * 16 + lg * 4);
  f32x4 bias2v[4];
  #pragma unroll
  for (int nt = 0; nt < 4; ++nt) bias2v[nt] = *(const f32x4*)(b2 + nt * 16 + lg * 4);
  const f32x4 b3v = *(const f32x4*)b3;   // used by lg==0 lanes

  WAVE_FENCE();   // A-rows of this wave visible (intra-wave DS is FIFO)

  for (int t = 0; t < 4; ++t) {
    // ---- layer 1: H1^T tiles = mfma(W1frag, Afrag) + b1, ReLU ----
    {
      short8 a = *(const short8*)(wsm + W_A + (t * 16 + l15) * 80 + lg * 16);
      f32x4 acc[8];
      #pragma unroll
      for (int nt = 0; nt < 8; ++nt)
        acc[nt] = __builtin_amdgcn_mfma_f32_16x16x32_bf16(bf1[nt], a, fzero, 0, 0, 0);
      #pragma unroll
      for (int nt = 0; nt < 8; ++nt) {
        short4v pk;
        #pragma unroll
        for (int j = 0; j < 4; ++j) {
          float h = acc[nt][j] + bias1v[nt][j];
          h = h > 0.0f ? h : 0.0f;
          pk[j] = f2bf(h);
        }
        *(short4v*)(wsm + W_H1 + l15 * 272 + (nt * 16 + lg * 4) * 2) = pk;
      }
    }
    WAVE_FENCE();

    // ---- layer 2: H2^T tiles = mfma(W2frag, H1frag) + b2, ReLU ----
    {
      f32x4 acc2[4] = {fzero, fzero, fzero, fzero};
      #pragma unroll
      for (int kt = 0; kt < 4; ++kt) {
        short8 a2 = *(const short8*)(wsm + W_H1 + l15 * 272 + kt * 64 + lg * 16);
        #pragma unroll
        for (int nt = 0; nt < 4; ++nt) {
          short8 bw;
          if constexpr (WF) {
            bw = wv4[(8 + kt * 4 + nt) * 64 + lane];
          } else {
            int col = nt * 16 + l15;
            #pragma unroll
            for (int j = 0; j < 8; ++j)
              bw[j] = f2bf(W2[(kt * 32 + lg * 8 + j) * 64 + col]);
          }
          acc2[nt] = __builtin_amdgcn_mfma_f32_16x16x32_bf16(bw, a2, acc2[nt], 0, 0, 0);
        }
      }
      #pragma unroll
      for (int nt = 0; nt < 4; ++nt) {
        short4v pk;
        #pragma unroll
        for (int j = 0; j < 4; ++j) {
          float h = acc2[nt][j] + bias2v[nt][j];
          h = h > 0.0f ? h : 0.0f;
          pk[j] = f2bf(h);
        }
        *(short4v*)(wsm + W_H2 + l15 * 144 + (nt * 16 + lg * 4) * 2) = pk;
      }
    }
    WAVE_FENCE();

    // ---- layer 3: delta^T = mfma(W3frag, H2frag) + b3 ----
    {
      f32x4 acc3 = fzero;
      #pragma unroll
      for (int kt = 0; kt < 2; ++kt) {
        short8 a3 = *(const short8*)(wsm + W_H2 + l15 * 144 + kt * 64 + lg * 16);
        short8 bw;
        if constexpr (WF) {
          bw = wv4[(24 + kt) * 64 + lane];
        } else {
          #pragma unroll
          for (int j = 0; j < 8; ++j)
            bw[j] = (l15 < 4) ? f2bf(W3[(kt * 32 + lg * 8 + j) * 4 + l15]) : (short)0;
        }
        acc3 = __builtin_amdgcn_mfma_f32_16x16x32_bf16(bw, a3, acc3, 0, 0, 0);
      }
      if (lg == 0) {
        float* dr = (float*)(wsm + W_D + (t * 16 + l15) * 20);
        #pragma unroll
        for (int j = 0; j < 4; ++j) dr[j] = acc3[j] + b3v[j];
      }
    }
    WAVE_FENCE();   // orders next t's H1 writes behind this t's H2/delta
  }
}

// ---------------- hot kernel (slim + in-kernel worklist append) -------------
__global__ __launch_bounds__(256, 2) void MatrixMLP_54047868453544_kernel(
    const float* __restrict__ x,
    const float* __restrict__ b1, const float* __restrict__ b2,
    const float* __restrict__ b3,
    const short* __restrict__ wfrag,
    int* __restrict__ wl_cnt, int* __restrict__ wl_list,
    int nbuck, int cap,
    float* __restrict__ out, int Bn)
{
  __shared__ __align__(16) unsigned char smem[SMEM_SZ];
  const int tid  = threadIdx.x;
  const int lane = tid & 63;
  const int wv   = tid >> 6;
  const int l15  = lane & 15;
  const int lg   = lane >> 4;
  unsigned char* wsm = smem + wv * W_SZ;
  const long long g = (long long)blockIdx.x * 256 + wv * 64 + lane;
  const f32x4 fzero = {0.0f, 0.0f, 0.0f, 0.0f};

  // ---- load row as named vectors ----
  f32x4 v0 = fzero, v1 = fzero, v2 = fzero, v3 = fzero, v4 = fzero;
  if (g < Bn) {
    const f32x4* xr = (const f32x4*)(x + g * 20);
    v0 = xr[0]; v1 = xr[1]; v2 = xr[2]; v3 = xr[3]; v4 = xr[4];
  }

  // ---- f32 Cramer solve with safety guard; all named scalars ----
  float a00 = v0[0], a10 = v0[1], a20 = v0[2], a30 = v0[3];
  float a01 = v1[0], a11 = v1[1], a21 = v1[2], a31 = v1[3];
  float a02 = v2[0], a12 = v2[1], a22 = v2[2], a32 = v2[3];
  float a03 = v3[0], a13 = v3[1], a23 = v3[2], a33 = v3[3];
  float y0 = v4[0], y1 = v4[1], y2 = v4[2], y3 = v4[3];

  float s0 = a00*a11 - a10*a01, s1 = a00*a12 - a10*a02, s2 = a00*a13 - a10*a03;
  float s3 = a01*a12 - a11*a02, s4 = a01*a13 - a11*a03, s5 = a02*a13 - a12*a03;
  float c0 = a20*a31 - a30*a21, c1 = a20*a32 - a30*a22, c2 = a20*a33 - a30*a23;
  float c3 = a21*a32 - a31*a22, c4 = a21*a33 - a31*a23, c5 = a22*a33 - a32*a23;
  float det = s0*c5 - s1*c4 + s2*c3 + s3*c2 - s4*c1 + s5*c0;
  float T = a00*a00 + a01*a01 + a02*a02 + a03*a03
          + a10*a10 + a11*a11 + a12*a12 + a13*a13
          + a20*a20 + a21*a21 + a22*a22 + a23*a23
          + a30*a30 + a31*a31 + a32*a32 + a33*a33;

  const bool safe = __builtin_fabsf(det) > GUARD_THETA * T * T;
  float xd0 = 0.0f, xd1 = 0.0f, xd2 = 0.0f, xd3 = 0.0f;
  if (safe) {
    float rdet = 1.0f / det;
    xd0 = rdet * ((  a11*c5 - a12*c4 + a13*c3) * y0 +
                  (-(a01*c5 - a02*c4 + a03*c3)) * y1 +
                  (  a31*s5 - a32*s4 + a33*s3) * y2 +
                  (-(a21*s5 - a22*s4 + a23*s3)) * y3);
    xd1 = rdet * ((-(a10*c5 - a12*c2 + a13*c1)) * y0 +
                  (  a00*c5 - a02*c2 + a03*c1) * y1 +
                  (-(a30*s5 - a32*s2 + a33*s1)) * y2 +
                  (  a20*s5 - a22*s2 + a23*s1) * y3);
    xd2 = rdet * ((  a10*c4 - a11*c2 + a13*c0) * y0 +
                  (-(a00*c4 - a01*c2 + a03*c0)) * y1 +
                  (  a30*s4 - a31*s2 + a33*s0) * y2 +
                  (-(a20*s4 - a21*s2 + a23*s0)) * y3);
    xd3 = rdet * ((-(a10*c3 - a11*c1 + a12*c0)) * y0 +
                  (  a00*c3 - a01*c1 + a02*c0) * y1 +
                  (-(a30*s3 - a31*s1 + a32*s0)) * y2 +
                  (  a20*s3 - a21*s1 + a22*s0) * y3);
  }
  // unsafe lanes keep xd=0: placeholder, overwritten by repair kernel

  // ---- worklist append: EXACT predicate, 1 bucketed atomic per wave ----
  if (wl_list) {
    const bool unsafe_row = (!safe) && (g < Bn);
    unsigned long long m = __ballot(unsafe_row);
    if (m) {
      const int bucket = (int)blockIdx.x % nbuck;
      int leader = (int)__builtin_ctzll(m);
      int base = 0;
      if (lane == leader)
        base = atomicAdd(&wl_cnt[bucket * 32], (int)__builtin_popcountll(m));
      base = __shfl(base, leader, 64);
      if (unsafe_row) {
        int lt = (int)__builtin_popcountll(m & ((1ull << lane) - 1ull));
        wl_list[(size_t)bucket * cap + base + lt] = (int)g;
      }
    }
  }

  const float xls0 = cl01(xd0), xls1 = cl01(xd1);
  const float xls2 = cl01(xd2), xls3 = cl01(xd3);

  // ---- A-row as named short8 vectors ----
  short8 r0 = { f2bf(v0[0]), f2bf(v0[1]), f2bf(v0[2]), f2bf(v0[3]),
                f2bf(v1[0]), f2bf(v1[1]), f2bf(v1[2]), f2bf(v1[3]) };
  short8 r1 = { f2bf(v2[0]), f2bf(v2[1]), f2bf(v2[2]), f2bf(v2[3]),
                f2bf(v3[0]), f2bf(v3[1]), f2bf(v3[2]), f2bf(v3[3]) };
  short8 r2 = { f2bf(v4[0]), f2bf(v4[1]), f2bf(v4[2]), f2bf(v4[3]),
                f2bf(xls0),  f2bf(xls1),  f2bf(xls2),  f2bf(xls3) };
  short8 r3 = { 0, 0, 0, 0, 0, 0, 0, 0 };
  {
    short8* dst = (short8*)(wsm + W_A + lane * 80);
    dst[0] = r0; dst[1] = r1; dst[2] = r2; dst[3] = r3;
  }

  // ---- MFMA MLP (wave-autonomous, transposed, preloaded biases) ----
  mlp_wave<true>(wsm, lane, l15, lg, (const short8*)wfrag,
                 nullptr, nullptr, nullptr, b1, b2, b3);

  // ---- epilogue ----
  if (g < Bn) {
    const float* dl = (const float*)(wsm + W_D + lane * 20);
    f32x4 o = { fminf(fmaxf(xls0 + dl[0], 0.0f), 1.0f),
                fminf(fmaxf(xls1 + dl[1], 0.0f), 1.0f),
                fminf(fmaxf(xls2 + dl[2], 0.0f), 1.0f),
                fminf(fmaxf(xls3 + dl[3], 0.0f), 1.0f) };
    *(f32x4*)(out + g * 4) = o;
  }
}

// ---------------- repair kernel (parallel buckets / full-scan fallback) -----
__global__ __launch_bounds__(256) void repair_rows(
    const float* __restrict__ x,
    const float* __restrict__ W1, const float* __restrict__ b1,
    const float* __restrict__ W2, const float* __restrict__ b2,
    const float* __restrict__ W3, const float* __restrict__ b3,
    const short* __restrict__ wfrag,
    float* __restrict__ out, int Bn,
    const int* __restrict__ wl_cnt, const int* __restrict__ wl_list,
    int use_wl, int nbuck, int cap, int write_all)
{
  __shared__ __align__(16) unsigned char smem[SMEM_SZ];
  const int tid  = threadIdx.x;
  const int lane = tid & 63;
  const int wv   = tid >> 6;
  const int l15  = lane & 15;
  const int lg   = lane >> 4;
  unsigned char* wsm = smem + wv * W_SZ;

  const int bucket = use_wl ? ((int)blockIdx.x % nbuck) : 0;
  const int sub    = use_wl ? ((int)blockIdx.x / nbuck) : (int)blockIdx.x;
  const int nsub   = use_wl ? ((int)gridDim.x / nbuck)  : (int)gridDim.x;
  const int cnt = use_wl ? wl_cnt[bucket * 32] : Bn;
  const int* lst = wl_list + (size_t)bucket * cap;

  for (long long blk0 = (long long)sub * 256; blk0 < cnt;
       blk0 += (long long)nsub * 256) {
    const long long idx = blk0 + tid;
    int g = -1;
    if (idx < cnt) g = use_wl ? lst[idx] : (int)idx;

    float xf[20];
    if (g >= 0) {
      const float* xr = x + (long long)g * 20;
      #pragma unroll
      for (int i = 0; i < 5; ++i) {
        f32x4 v = *(const f32x4*)(xr + i * 4);
        xf[i*4+0] = v[0]; xf[i*4+1] = v[1]; xf[i*4+2] = v[2]; xf[i*4+3] = v[3];
      }
    } else {
      #pragma unroll
      for (int i = 0; i < 20; ++i) xf[i] = 0.0f;
    }

    if (!use_wl && !write_all && g >= 0) {
      // scan fallback with hot kernel present: keep only guard-failing rows
      float a00 = xf[0], a01 = xf[4], a02 = xf[8],  a03 = xf[12];
      float a10 = xf[1], a11 = xf[5], a12 = xf[9],  a13 = xf[13];
      float a20 = xf[2], a21 = xf[6], a22 = xf[10], a23 = xf[14];
      float a30 = xf[3], a31 = xf[7], a32 = xf[11], a33 = xf[15];
      float s0 = a00*a11 - a10*a01, s1 = a00*a12 - a10*a02, s2 = a00*a13 - a10*a03;
      float s3 = a01*a12 - a11*a02, s4 = a01*a13 - a11*a03, s5 = a02*a13 - a12*a03;
      float c0 = a20*a31 - a30*a21, c1 = a20*a32 - a30*a22, c2 = a20*a33 - a30*a23;
      float c3 = a21*a32 - a31*a22, c4 = a21*a33 - a31*a23, c5 = a22*a33 - a32*a23;
      float det = s0*c5 - s1*c4 + s2*c3 + s3*c2 - s4*c1 + s5*c0;
      float T = a00*a00 + a01*a01 + a02*a02 + a03*a03
              + a10*a10 + a11*a11 + a12*a12 + a13*a13
              + a20*a20 + a21*a21 + a22*a22 + a23*a23
              + a30*a30 + a31*a31 + a32*a32 + a33*a33;
      if (__builtin_fabsf(det) > GUARD_THETA * 1.004f * T * T) g = -1;
    }

    // ---- f64 Jacobi eigensolve of G = H^T H + jax rcond truncation ----
    double G[4][4], V[4][4], rhs[4];
    #pragma unroll
    for (int p = 0; p < 4; ++p) {
      #pragma unroll
      for (int q = 0; q < 4; ++q) {
        double s = 0.0;
        #pragma unroll
        for (int k = 0; k < 4; ++k)
          s += (double)xf[p * 4 + k] * (double)xf[q * 4 + k];
        G[p][q] = s;
        V[p][q] = (p == q) ? 1.0 : 0.0;
      }
      double s = 0.0;
      #pragma unroll
      for (int k = 0; k < 4; ++k) s += (double)xf[p * 4 + k] * (double)xf[16 + k];
      rhs[p] = s;
    }
    #pragma unroll 1
    for (int sweep = 0; sweep < 6; ++sweep) {
      #pragma unroll
      for (int pq = 0; pq < 6; ++pq) {
        constexpr int PP[6] = {0, 0, 0, 1, 1, 2};
        constexpr int QQ[6] = {1, 2, 3, 2, 3, 3};
        const int p = PP[pq], q = QQ[pq];
        double apq = G[p][q];
        double c, s;
        if (apq != 0.0) {
          double tau = (G[q][q] - G[p][p]) / (2.0 * apq);
          double t = (tau >= 0.0 ? 1.0 : -1.0) / (fabs(tau) + sqrt(1.0 + tau * tau));
          c = 1.0 / sqrt(1.0 + t * t);
          s = t * c;
        } else { c = 1.0; s = 0.0; }
        #pragma unroll
        for (int k = 0; k < 4; ++k) {
          double gpk = G[p][k], gqk = G[q][k];
          G[p][k] = c * gpk - s * gqk;
          G[q][k] = s * gpk + c * gqk;
        }
        #pragma unroll
        for (int k = 0; k < 4; ++k) {
          double gkp = G[k][p], gkq = G[k][q];
          G[k][p] = c * gkp - s * gkq;
          G[k][q] = s * gkp + c * gkq;
        }
        #pragma unroll
        for (int k = 0; k < 4; ++k) {
          double vkp = V[k][p], vkq = V[k][q];
          V[k][p] = c * vkp - s * vkq;
          V[k][q] = s * vkp + c * vkq;
        }
      }
    }
    double lam[4] = {G[0][0], G[1][1], G[2][2], G[3][3]};
    double lmax = fmax(fmax(lam[0], lam[1]), fmax(lam[2], lam[3]));
    lmax = fmax(lmax, 0.0);
    const double cut = 2.27373675443232e-11 * lmax;  // (4.7683716e-6)^2
    double xd0 = 0.0, xd1 = 0.0, xd2 = 0.0, xd3 = 0.0;
    #pragma unroll
    for (int k = 0; k < 4; ++k) {
      if (lam[k] > cut && lam[k] > 0.0) {
        double coef = (V[0][k] * rhs[0] + V[1][k] * rhs[1] +
                       V[2][k] * rhs[2] + V[3][k] * rhs[3]) / lam[k];
        xd0 += V[0][k] * coef;
        xd1 += V[1][k] * coef;
        xd2 += V[2][k] * coef;
        xd3 += V[3][k] * coef;
      }
    }

    float xls[4];
    {
      double xd[4] = {xd0, xd1, xd2, xd3};
      short rowbuf[32];
      #pragma unroll
      for (int i = 0; i < 20; ++i) rowbuf[i] = f2bf(xf[i]);
      #pragma unroll
      for (int i = 0; i < 4; ++i) {
        float v = (float)xd[i];
        if (v != v) v = 0.0f;
        v = fminf(fmaxf(v, 0.0f), 1.0f);
        xls[i] = v;
        rowbuf[20 + i] = f2bf(v);
      }
      #pragma unroll
      for (int i = 24; i < 32; ++i) rowbuf[i] = 0;
      short8* dst = (short8*)(wsm + W_A + lane * 80);
      #pragma unroll
      for (int i = 0; i < 4; ++i) dst[i] = *(short8*)(rowbuf + i * 8);
    }

    if (wfrag)
      mlp_wave<true>(wsm, lane, l15, lg, (const short8*)wfrag,
                     W1, W2, W3, b1, b2, b3);
    else
      mlp_wave<false>(wsm, lane, l15, lg, nullptr,
                      W1, W2, W3, b1, b2, b3);

    if (g >= 0) {
      const float* dl = (const float*)(wsm + W_D + lane * 20);
      f32x4 o = { fminf(fmaxf(xls[0] + dl[0], 0.0f), 1.0f),
                  fminf(fmaxf(xls[1] + dl[1], 0.0f), 1.0f),
                  fminf(fmaxf(xls[2] + dl[2], 0.0f), 1.0f),
                  fminf(fmaxf(xls[3] + dl[3], 0.0f), 1.0f) };
      *(f32x4*)(out + (long long)g * 4) = o;
    }
  }
}

extern "C" void kernel_launch(void* const* d_in, const int* in_sizes, int n_in,
                              void* d_out, int out_size, void* d_ws, size_t ws_size,
                              hipStream_t stream) {
  (void)n_in;
  const float* x  = (const float*)d_in[0];
  const float* W1 = (const float*)d_in[1];
  const float* b1 = (const float*)d_in[2];
  const float* W2 = (const float*)d_in[3];
  const float* b2 = (const float*)d_in[4];
  const float* W3 = (const float*)d_in[5];
  const float* b3 = (const float*)d_in[6];
  float* out = (float*)d_out;
  const int Bn = in_sizes[0] / 20;
  const int nblk = (Bn + 255) / 256;

  short* wfrag = nullptr;
  int* wl_cnt = nullptr;
  int* wl_list = nullptr;
  int use_wl = 0, nbuck = 1, cap = 0;
  if (ws_size >= (size_t)WFRAG_BYTES) wfrag = (short*)d_ws;
  {
    int cap32 = 256 * ((nblk + NBUCK - 1) / NBUCK);
    int cap1  = 256 * nblk;
    if (ws_size >= (size_t)WL_LIST_OFF + 4ull * NBUCK * (size_t)cap32) {
      nbuck = NBUCK; cap = cap32; use_wl = 1;
    } else if (ws_size >= (size_t)WL_LIST_OFF + 4ull * (size_t)cap1) {
      nbuck = 1; cap = cap1; use_wl = 1;
    }
    if (use_wl) {
      wl_cnt  = (int*)((char*)d_ws + WL_CNT_OFF);
      wl_list = (int*)((char*)d_ws + WL_LIST_OFF);
    }
  }

  (void)hipGetLastError();

  if (wfrag) {
    pack_w<<<7, 256, 0, stream>>>(W1, W2, W3, wfrag, wl_cnt);
    MatrixMLP_54047868453544_kernel<<<nblk, 256, 0, stream>>>(
        x, b1, b2, b3, wfrag,
        use_wl ? wl_cnt : nullptr, use_wl ? wl_list : nullptr,
        nbuck, cap, out, Bn);
    const int rblk = use_wl ? (nbuck * (RBLK / NBUCK)) : RBLK;
    repair_rows<<<rblk, 256, 0, stream>>>(x, W1, b1, W2, b2, W3, b3, wfrag,
                                          out, Bn, wl_cnt, wl_list,
                                          use_wl, nbuck, cap, /*write_all=*/0);
  } else {
    // ws too small for weight fragments (never observed): full Jacobi+MFMA
    // pass over ALL rows -- slow but correct.
    repair_rows<<<RBLK, 256, 0, stream>>>(x, W1, b1, W2, b2, W3, b3, nullptr,
                                          out, Bn, nullptr, nullptr,
                                          /*use_wl=*/0, 1, 0, /*write_all=*/1);
  }

  hipError_t e = hipGetLastError();
  if (e != hipSuccess) {
    int byte = 0x40 + ((int)e & 63);
    hipMemsetAsync(d_out, byte, (size_t)out_size * sizeof(float), stream);
  }
}

// Round 18
// 62.101 us; speedup vs baseline: 1.1108x; 1.0422x over previous
//
#include <hip/hip_runtime.h>

// MatrixMLP round 18 (FINAL): revert to round 14 verbatim -- the session's
// best-measured configuration (61.8us, 20.7x over the first passing kernel).
//  - r15-r17 (transposed MFMA, wave fences, bias preload) all failed to beat
//    it (64.7-69.0us); latency-bound regime where those levers don't bite.
//  - Pipeline: pack_w -> hot (f32 Cramer solve + worklist append + bf16-MFMA
//    MLP, slim/no-alloca codegen) -> repair (wave-parallel f64 Jacobi + MFMA
//    over dense bucketed worklist).

typedef __attribute__((ext_vector_type(8))) short short8;
typedef __attribute__((ext_vector_type(4))) float f32x4;

__device__ __forceinline__ short f2bf(float f) {
  unsigned int u = __float_as_uint(f);
  u += 0x7fffu + ((u >> 16) & 1u);
  return (short)(u >> 16);
}
__device__ __forceinline__ float cl01(float v) {
  if (v != v) v = 0.0f;
  return fminf(fmaxf(v, 0.0f), 1.0f);
}

#define GUARD_THETA 1.0e-4f
#define WFRAG_BYTES 26624        // 26 frags * 64 lanes * 16 B
#define WL_CNT_OFF  26624        // 32 counters, stride 32 ints (128 B)
#define WL_LIST_OFF 30720
#define NBUCK 32
#define RBLK 256

// ---- per-wave LDS chunk (bytes) ----
#define W_A    0        // 64 rows * 80 B
#define W_H1   5120     // 16 rows * 272 B
#define W_H2   9472     // 16 rows * 144 B
#define W_D    11776    // 64 rows * 20 B
#define W_SZ   13056
#define SMEM_SZ (4 * W_SZ)   // 52224 B -> 3 blocks/CU

// ---------------- weight fragment pre-pack (+ counter reset) ----------------
__global__ void pack_w(const float* __restrict__ W1, const float* __restrict__ W2,
                       const float* __restrict__ W3, short* __restrict__ ws,
                       int* __restrict__ wl_cnt)
{
  if (wl_cnt && blockIdx.x == 0 && threadIdx.x < NBUCK)
    wl_cnt[threadIdx.x * 32] = 0;
  int t = blockIdx.x * 256 + threadIdx.x;
  if (t >= 26 * 64) return;
  int fid = t >> 6, lane = t & 63, l15 = lane & 15, lg = lane >> 4;
  short8 v;
  if (fid < 8) {
    int col = fid * 16 + l15;
    #pragma unroll
    for (int j = 0; j < 8; ++j) {
      int k = lg * 8 + j;
      v[j] = (k < 24) ? f2bf(W1[k * 128 + col]) : (short)0;
    }
  } else if (fid < 24) {
    int q = fid - 8, kt = q >> 2, nt = q & 3, col = nt * 16 + l15;
    #pragma unroll
    for (int j = 0; j < 8; ++j)
      v[j] = f2bf(W2[(kt * 32 + lg * 8 + j) * 64 + col]);
  } else {
    int kt = fid - 24;
    #pragma unroll
    for (int j = 0; j < 8; ++j)
      v[j] = (l15 < 4) ? f2bf(W3[(kt * 32 + lg * 8 + j) * 4 + l15]) : (short)0;
  }
  ((short8*)ws)[t] = v;
}

// ---------------- shared MFMA MLP body (barrier-synced) ----------------
template <bool WF>
__device__ __forceinline__ void mlp_wave(
    unsigned char* wsm, int lane, int l15, int lg,
    const short8* __restrict__ wv4,
    const float* __restrict__ W1, const float* __restrict__ W2,
    const float* __restrict__ W3,
    const float* __restrict__ b1, const float* __restrict__ b2,
    const float* __restrict__ b3)
{
  const f32x4 fzero = {0.0f, 0.0f, 0.0f, 0.0f};

  short8 bf1[8];
  if constexpr (WF) {
    #pragma unroll
    for (int nt = 0; nt < 8; ++nt) bf1[nt] = wv4[nt * 64 + lane];
  } else {
    #pragma unroll
    for (int nt = 0; nt < 8; ++nt) {
      int col = nt * 16 + l15;
      #pragma unroll
      for (int j = 0; j < 8; ++j) {
        int k = lg * 8 + j;
        bf1[nt][j] = (k < 24) ? f2bf(W1[k * 128 + col]) : (short)0;
      }
    }
  }
  float bias1[8], bias2[4], bias3;
  #pragma unroll
  for (int nt = 0; nt < 8; ++nt) bias1[nt] = b1[nt * 16 + l15];
  #pragma unroll
  for (int nt = 0; nt < 4; ++nt) bias2[nt] = b2[nt * 16 + l15];
  bias3 = b3[l15 & 3];

  __syncthreads();   // A-rows visible

  for (int t = 0; t < 4; ++t) {
    // layer 1: (16x32)@(32x128) + b1, ReLU -> H1 tile
    {
      short8 a = *(const short8*)(wsm + W_A + (t * 16 + l15) * 80 + lg * 16);
      f32x4 acc[8];
      #pragma unroll
      for (int nt = 0; nt < 8; ++nt)
        acc[nt] = __builtin_amdgcn_mfma_f32_16x16x32_bf16(a, bf1[nt], fzero, 0, 0, 0);
      #pragma unroll
      for (int nt = 0; nt < 8; ++nt) {
        #pragma unroll
        for (int j = 0; j < 4; ++j) {
          float h = acc[nt][j] + bias1[nt];
          h = h > 0.0f ? h : 0.0f;
          *(short*)(wsm + W_H1 + (lg * 4 + j) * 272 + (nt * 16 + l15) * 2) = f2bf(h);
        }
      }
    }
    __syncthreads();

    // layer 2: (16x128)@(128x64) + b2, ReLU -> H2 tile
    {
      f32x4 acc2[4] = {fzero, fzero, fzero, fzero};
      #pragma unroll
      for (int kt = 0; kt < 4; ++kt) {
        short8 a2 = *(const short8*)(wsm + W_H1 + l15 * 272 + kt * 64 + lg * 16);
        #pragma unroll
        for (int nt = 0; nt < 4; ++nt) {
          short8 bw;
          if constexpr (WF) {
            bw = wv4[(8 + kt * 4 + nt) * 64 + lane];
          } else {
            int col = nt * 16 + l15;
            #pragma unroll
            for (int j = 0; j < 8; ++j)
              bw[j] = f2bf(W2[(kt * 32 + lg * 8 + j) * 64 + col]);
          }
          acc2[nt] = __builtin_amdgcn_mfma_f32_16x16x32_bf16(a2, bw, acc2[nt], 0, 0, 0);
        }
      }
      #pragma unroll
      for (int nt = 0; nt < 4; ++nt) {
        #pragma unroll
        for (int j = 0; j < 4; ++j) {
          float h = acc2[nt][j] + bias2[nt];
          h = h > 0.0f ? h : 0.0f;
          *(short*)(wsm + W_H2 + (lg * 4 + j) * 144 + (nt * 16 + l15) * 2) = f2bf(h);
        }
      }
    }
    __syncthreads();

    // layer 3: (16x64)@(64x16[4]) + b3 -> delta
    {
      f32x4 acc3 = fzero;
      #pragma unroll
      for (int kt = 0; kt < 2; ++kt) {
        short8 a3 = *(const short8*)(wsm + W_H2 + l15 * 144 + kt * 64 + lg * 16);
        short8 bw;
        if constexpr (WF) {
          bw = wv4[(24 + kt) * 64 + lane];
        } else {
          #pragma unroll
          for (int j = 0; j < 8; ++j)
            bw[j] = (l15 < 4) ? f2bf(W3[(kt * 32 + lg * 8 + j) * 4 + l15]) : (short)0;
        }
        acc3 = __builtin_amdgcn_mfma_f32_16x16x32_bf16(a3, bw, acc3, 0, 0, 0);
      }
      if (l15 < 4) {
        #pragma unroll
        for (int j = 0; j < 4; ++j)
          *(float*)(wsm + W_D + (t * 16 + lg * 4 + j) * 20 + l15 * 4) = acc3[j] + bias3;
      }
    }
  }
  __syncthreads();   // delta visible
}

// ---------------- hot kernel (slim + in-kernel worklist append) -------------
__global__ __launch_bounds__(256, 2) void MatrixMLP_54047868453544_kernel(
    const float* __restrict__ x,
    const float* __restrict__ b1, const float* __restrict__ b2,
    const float* __restrict__ b3,
    const short* __restrict__ wfrag,
    int* __restrict__ wl_cnt, int* __restrict__ wl_list,
    int nbuck, int cap,
    float* __restrict__ out, int Bn)
{
  __shared__ __align__(16) unsigned char smem[SMEM_SZ];
  const int tid  = threadIdx.x;
  const int lane = tid & 63;
  const int wv   = tid >> 6;
  const int l15  = lane & 15;
  const int lg   = lane >> 4;
  unsigned char* wsm = smem + wv * W_SZ;
  const long long g = (long long)blockIdx.x * 256 + wv * 64 + lane;
  const f32x4 fzero = {0.0f, 0.0f, 0.0f, 0.0f};

  // ---- load row as named vectors ----
  f32x4 v0 = fzero, v1 = fzero, v2 = fzero, v3 = fzero, v4 = fzero;
  if (g < Bn) {
    const f32x4* xr = (const f32x4*)(x + g * 20);
    v0 = xr[0]; v1 = xr[1]; v2 = xr[2]; v3 = xr[3]; v4 = xr[4];
  }

  // ---- f32 Cramer solve with safety guard; all named scalars ----
  float a00 = v0[0], a10 = v0[1], a20 = v0[2], a30 = v0[3];
  float a01 = v1[0], a11 = v1[1], a21 = v1[2], a31 = v1[3];
  float a02 = v2[0], a12 = v2[1], a22 = v2[2], a32 = v2[3];
  float a03 = v3[0], a13 = v3[1], a23 = v3[2], a33 = v3[3];
  float y0 = v4[0], y1 = v4[1], y2 = v4[2], y3 = v4[3];

  float s0 = a00*a11 - a10*a01, s1 = a00*a12 - a10*a02, s2 = a00*a13 - a10*a03;
  float s3 = a01*a12 - a11*a02, s4 = a01*a13 - a11*a03, s5 = a02*a13 - a12*a03;
  float c0 = a20*a31 - a30*a21, c1 = a20*a32 - a30*a22, c2 = a20*a33 - a30*a23;
  float c3 = a21*a32 - a31*a22, c4 = a21*a33 - a31*a23, c5 = a22*a33 - a32*a23;
  float det = s0*c5 - s1*c4 + s2*c3 + s3*c2 - s4*c1 + s5*c0;
  float T = a00*a00 + a01*a01 + a02*a02 + a03*a03
          + a10*a10 + a11*a11 + a12*a12 + a13*a13
          + a20*a20 + a21*a21 + a22*a22 + a23*a23
          + a30*a30 + a31*a31 + a32*a32 + a33*a33;

  const bool safe = __builtin_fabsf(det) > GUARD_THETA * T * T;
  float xd0 = 0.0f, xd1 = 0.0f, xd2 = 0.0f, xd3 = 0.0f;
  if (safe) {
    float rdet = 1.0f / det;
    xd0 = rdet * ((  a11*c5 - a12*c4 + a13*c3) * y0 +
                  (-(a01*c5 - a02*c4 + a03*c3)) * y1 +
                  (  a31*s5 - a32*s4 + a33*s3) * y2 +
                  (-(a21*s5 - a22*s4 + a23*s3)) * y3);
    xd1 = rdet * ((-(a10*c5 - a12*c2 + a13*c1)) * y0 +
                  (  a00*c5 - a02*c2 + a03*c1) * y1 +
                  (-(a30*s5 - a32*s2 + a33*s1)) * y2 +
                  (  a20*s5 - a22*s2 + a23*s1) * y3);
    xd2 = rdet * ((  a10*c4 - a11*c2 + a13*c0) * y0 +
                  (-(a00*c4 - a01*c2 + a03*c0)) * y1 +
                  (  a30*s4 - a31*s2 + a33*s0) * y2 +
                  (-(a20*s4 - a21*s2 + a23*s0)) * y3);
    xd3 = rdet * ((-(a10*c3 - a11*c1 + a12*c0)) * y0 +
                  (  a00*c3 - a01*c1 + a02*c0) * y1 +
                  (-(a30*s3 - a31*s1 + a32*s0)) * y2 +
                  (  a20*s3 - a21*s1 + a22*s0) * y3);
  }
  // unsafe lanes keep xd=0: placeholder, overwritten by repair kernel

  // ---- worklist append: EXACT predicate, 1 bucketed atomic per wave ----
  if (wl_list) {
    const bool unsafe_row = (!safe) && (g < Bn);
    unsigned long long m = __ballot(unsafe_row);
    if (m) {
      const int bucket = (int)blockIdx.x % nbuck;
      int leader = (int)__builtin_ctzll(m);
      int base = 0;
      if (lane == leader)
        base = atomicAdd(&wl_cnt[bucket * 32], (int)__builtin_popcountll(m));
      base = __shfl(base, leader, 64);
      if (unsafe_row) {
        int lt = (int)__builtin_popcountll(m & ((1ull << lane) - 1ull));
        wl_list[(size_t)bucket * cap + base + lt] = (int)g;
      }
    }
  }

  const float xls0 = cl01(xd0), xls1 = cl01(xd1);
  const float xls2 = cl01(xd2), xls3 = cl01(xd3);

  // ---- A-row as named short8 vectors ----
  short8 r0 = { f2bf(v0[0]), f2bf(v0[1]), f2bf(v0[2]), f2bf(v0[3]),
                f2bf(v1[0]), f2bf(v1[1]), f2bf(v1[2]), f2bf(v1[3]) };
  short8 r1 = { f2bf(v2[0]), f2bf(v2[1]), f2bf(v2[2]), f2bf(v2[3]),
                f2bf(v3[0]), f2bf(v3[1]), f2bf(v3[2]), f2bf(v3[3]) };
  short8 r2 = { f2bf(v4[0]), f2bf(v4[1]), f2bf(v4[2]), f2bf(v4[3]),
                f2bf(xls0),  f2bf(xls1),  f2bf(xls2),  f2bf(xls3) };
  short8 r3 = { 0, 0, 0, 0, 0, 0, 0, 0 };
  {
    short8* dst = (short8*)(wsm + W_A + lane * 80);
    dst[0] = r0; dst[1] = r1; dst[2] = r2; dst[3] = r3;
  }

  // ---- MFMA MLP ----
  mlp_wave<true>(wsm, lane, l15, lg, (const short8*)wfrag,
                 nullptr, nullptr, nullptr, b1, b2, b3);

  // ---- epilogue ----
  if (g < Bn) {
    const float* dl = (const float*)(wsm + W_D + lane * 20);
    f32x4 o = { fminf(fmaxf(xls0 + dl[0], 0.0f), 1.0f),
                fminf(fmaxf(xls1 + dl[1], 0.0f), 1.0f),
                fminf(fmaxf(xls2 + dl[2], 0.0f), 1.0f),
                fminf(fmaxf(xls3 + dl[3], 0.0f), 1.0f) };
    *(f32x4*)(out + g * 4) = o;
  }
}

// ---------------- repair kernel (parallel buckets / full-scan fallback) -----
__global__ __launch_bounds__(256) void repair_rows(
    const float* __restrict__ x,
    const float* __restrict__ W1, const float* __restrict__ b1,
    const float* __restrict__ W2, const float* __restrict__ b2,
    const float* __restrict__ W3, const float* __restrict__ b3,
    const short* __restrict__ wfrag,
    float* __restrict__ out, int Bn,
    const int* __restrict__ wl_cnt, const int* __restrict__ wl_list,
    int use_wl, int nbuck, int cap, int write_all)
{
  __shared__ __align__(16) unsigned char smem[SMEM_SZ];
  const int tid  = threadIdx.x;
  const int lane = tid & 63;
  const int wv   = tid >> 6;
  const int l15  = lane & 15;
  const int lg   = lane >> 4;
  unsigned char* wsm = smem + wv * W_SZ;

  const int bucket = use_wl ? ((int)blockIdx.x % nbuck) : 0;
  const int sub    = use_wl ? ((int)blockIdx.x / nbuck) : (int)blockIdx.x;
  const int nsub   = use_wl ? ((int)gridDim.x / nbuck)  : (int)gridDim.x;
  const int cnt = use_wl ? wl_cnt[bucket * 32] : Bn;
  const int* lst = wl_list + (size_t)bucket * cap;

  for (long long blk0 = (long long)sub * 256; blk0 < cnt;
       blk0 += (long long)nsub * 256) {
    const long long idx = blk0 + tid;
    int g = -1;
    if (idx < cnt) g = use_wl ? lst[idx] : (int)idx;

    float xf[20];
    if (g >= 0) {
      const float* xr = x + (long long)g * 20;
      #pragma unroll
      for (int i = 0; i < 5; ++i) {
        f32x4 v = *(const f32x4*)(xr + i * 4);
        xf[i*4+0] = v[0]; xf[i*4+1] = v[1]; xf[i*4+2] = v[2]; xf[i*4+3] = v[3];
      }
    } else {
      #pragma unroll
      for (int i = 0; i < 20; ++i) xf[i] = 0.0f;
    }

    if (!use_wl && !write_all && g >= 0) {
      // scan fallback with hot kernel present: keep only guard-failing rows
      float a00 = xf[0], a01 = xf[4], a02 = xf[8],  a03 = xf[12];
      float a10 = xf[1], a11 = xf[5], a12 = xf[9],  a13 = xf[13];
      float a20 = xf[2], a21 = xf[6], a22 = xf[10], a23 = xf[14];
      float a30 = xf[3], a31 = xf[7], a32 = xf[11], a33 = xf[15];
      float s0 = a00*a11 - a10*a01, s1 = a00*a12 - a10*a02, s2 = a00*a13 - a10*a03;
      float s3 = a01*a12 - a11*a02, s4 = a01*a13 - a11*a03, s5 = a02*a13 - a12*a03;
      float c0 = a20*a31 - a30*a21, c1 = a20*a32 - a30*a22, c2 = a20*a33 - a30*a23;
      float c3 = a21*a32 - a31*a22, c4 = a21*a33 - a31*a23, c5 = a22*a33 - a32*a23;
      float det = s0*c5 - s1*c4 + s2*c3 + s3*c2 - s4*c1 + s5*c0;
      float T = a00*a00 + a01*a01 + a02*a02 + a03*a03
              + a10*a10 + a11*a11 + a12*a12 + a13*a13
              + a20*a20 + a21*a21 + a22*a22 + a23*a23
              + a30*a30 + a31*a31 + a32*a32 + a33*a33;
      if (__builtin_fabsf(det) > GUARD_THETA * 1.004f * T * T) g = -1;
    }

    // ---- f64 Jacobi eigensolve of G = H^T H + jax rcond truncation ----
    double G[4][4], V[4][4], rhs[4];
    #pragma unroll
    for (int p = 0; p < 4; ++p) {
      #pragma unroll
      for (int q = 0; q < 4; ++q) {
        double s = 0.0;
        #pragma unroll
        for (int k = 0; k < 4; ++k)
          s += (double)xf[p * 4 + k] * (double)xf[q * 4 + k];
        G[p][q] = s;
        V[p][q] = (p == q) ? 1.0 : 0.0;
      }
      double s = 0.0;
      #pragma unroll
      for (int k = 0; k < 4; ++k) s += (double)xf[p * 4 + k] * (double)xf[16 + k];
      rhs[p] = s;
    }
    #pragma unroll 1
    for (int sweep = 0; sweep < 6; ++sweep) {
      #pragma unroll
      for (int pq = 0; pq < 6; ++pq) {
        constexpr int PP[6] = {0, 0, 0, 1, 1, 2};
        constexpr int QQ[6] = {1, 2, 3, 2, 3, 3};
        const int p = PP[pq], q = QQ[pq];
        double apq = G[p][q];
        double c, s;
        if (apq != 0.0) {
          double tau = (G[q][q] - G[p][p]) / (2.0 * apq);
          double t = (tau >= 0.0 ? 1.0 : -1.0) / (fabs(tau) + sqrt(1.0 + tau * tau));
          c = 1.0 / sqrt(1.0 + t * t);
          s = t * c;
        } else { c = 1.0; s = 0.0; }
        #pragma unroll
        for (int k = 0; k < 4; ++k) {
          double gpk = G[p][k], gqk = G[q][k];
          G[p][k] = c * gpk - s * gqk;
          G[q][k] = s * gpk + c * gqk;
        }
        #pragma unroll
        for (int k = 0; k < 4; ++k) {
          double gkp = G[k][p], gkq = G[k][q];
          G[k][p] = c * gkp - s * gkq;
          G[k][q] = s * gkp + c * gkq;
        }
        #pragma unroll
        for (int k = 0; k < 4; ++k) {
          double vkp = V[k][p], vkq = V[k][q];
          V[k][p] = c * vkp - s * vkq;
          V[k][q] = s * vkp + c * vkq;
        }
      }
    }
    double lam[4] = {G[0][0], G[1][1], G[2][2], G[3][3]};
    double lmax = fmax(fmax(lam[0], lam[1]), fmax(lam[2], lam[3]));
    lmax = fmax(lmax, 0.0);
    const double cut = 2.27373675443232e-11 * lmax;  // (4.7683716e-6)^2
    double xd0 = 0.0, xd1 = 0.0, xd2 = 0.0, xd3 = 0.0;
    #pragma unroll
    for (int k = 0; k < 4; ++k) {
      if (lam[k] > cut && lam[k] > 0.0) {
        double coef = (V[0][k] * rhs[0] + V[1][k] * rhs[1] +
                       V[2][k] * rhs[2] + V[3][k] * rhs[3]) / lam[k];
        xd0 += V[0][k] * coef;
        xd1 += V[1][k] * coef;
        xd2 += V[2][k] * coef;
        xd3 += V[3][k] * coef;
      }
    }

    float xls[4];
    {
      double xd[4] = {xd0, xd1, xd2, xd3};
      short rowbuf[32];
      #pragma unroll
      for (int i = 0; i < 20; ++i) rowbuf[i] = f2bf(xf[i]);
      #pragma unroll
      for (int i = 0; i < 4; ++i) {
        float v = (float)xd[i];
        if (v != v) v = 0.0f;
        v = fminf(fmaxf(v, 0.0f), 1.0f);
        xls[i] = v;
        rowbuf[20 + i] = f2bf(v);
      }
      #pragma unroll
      for (int i = 24; i < 32; ++i) rowbuf[i] = 0;
      short8* dst = (short8*)(wsm + W_A + lane * 80);
      #pragma unroll
      for (int i = 0; i < 4; ++i) dst[i] = *(short8*)(rowbuf + i * 8);
    }

    if (wfrag)
      mlp_wave<true>(wsm, lane, l15, lg, (const short8*)wfrag,
                     W1, W2, W3, b1, b2, b3);
    else
      mlp_wave<false>(wsm, lane, l15, lg, nullptr,
                      W1, W2, W3, b1, b2, b3);

    if (g >= 0) {
      const float* dl = (const float*)(wsm + W_D + lane * 20);
      f32x4 o = { fminf(fmaxf(xls[0] + dl[0], 0.0f), 1.0f),
                  fminf(fmaxf(xls[1] + dl[1], 0.0f), 1.0f),
                  fminf(fmaxf(xls[2] + dl[2], 0.0f), 1.0f),
                  fminf(fmaxf(xls[3] + dl[3], 0.0f), 1.0f) };
      *(f32x4*)(out + (long long)g * 4) = o;
    }
  }
}

extern "C" void kernel_launch(void* const* d_in, const int* in_sizes, int n_in,
                              void* d_out, int out_size, void* d_ws, size_t ws_size,
                              hipStream_t stream) {
  (void)n_in;
  const float* x  = (const float*)d_in[0];
  const float* W1 = (const float*)d_in[1];
  const float* b1 = (const float*)d_in[2];
  const float* W2 = (const float*)d_in[3];
  const float* b2 = (const float*)d_in[4];
  const float* W3 = (const float*)d_in[5];
  const float* b3 = (const float*)d_in[6];
  float* out = (float*)d_out;
  const int Bn = in_sizes[0] / 20;
  const int nblk = (Bn + 255) / 256;

  short* wfrag = nullptr;
  int* wl_cnt = nullptr;
  int* wl_list = nullptr;
  int use_wl = 0, nbuck = 1, cap = 0;
  if (ws_size >= (size_t)WFRAG_BYTES) wfrag = (short*)d_ws;
  {
    int cap32 = 256 * ((nblk + NBUCK - 1) / NBUCK);
    int cap1  = 256 * nblk;
    if (ws_size >= (size_t)WL_LIST_OFF + 4ull * NBUCK * (size_t)cap32) {
      nbuck = NBUCK; cap = cap32; use_wl = 1;
    } else if (ws_size >= (size_t)WL_LIST_OFF + 4ull * (size_t)cap1) {
      nbuck = 1; cap = cap1; use_wl = 1;
    }
    if (use_wl) {
      wl_cnt  = (int*)((char*)d_ws + WL_CNT_OFF);
      wl_list = (int*)((char*)d_ws + WL_LIST_OFF);
    }
  }

  (void)hipGetLastError();

  if (wfrag) {
    pack_w<<<7, 256, 0, stream>>>(W1, W2, W3, wfrag, wl_cnt);
    MatrixMLP_54047868453544_kernel<<<nblk, 256, 0, stream>>>(
        x, b1, b2, b3, wfrag,
        use_wl ? wl_cnt : nullptr, use_wl ? wl_list : nullptr,
        nbuck, cap, out, Bn);
    const int rblk = use_wl ? (nbuck * (RBLK / NBUCK)) : RBLK;
    repair_rows<<<rblk, 256, 0, stream>>>(x, W1, b1, W2, b2, W3, b3, wfrag,
                                          out, Bn, wl_cnt, wl_list,
                                          use_wl, nbuck, cap, /*write_all=*/0);
  } else {
    // ws too small for weight fragments (never observed): full Jacobi+MFMA
    // pass over ALL rows -- slow but correct.
    repair_rows<<<RBLK, 256, 0, stream>>>(x, W1, b1, W2, b2, W3, b3, nullptr,
                                          out, Bn, nullptr, nullptr,
                                          /*use_wl=*/0, 1, 0, /*write_all=*/1);
  }

  hipError_t e = hipGetLastError();
  if (e != hipSuccess) {
    int byte = 0x40 + ((int)e & 63);
    hipMemsetAsync(d_out, byte, (size_t)out_size * sizeof(float), stream);
  }
}